// Round 5
// baseline (718.044 us; speedup 1.0000x reference)
//
#include <hip/hip_runtime.h>
#include <math.h>

#define DEV __device__ __forceinline__

typedef float f4 __attribute__((ext_vector_type(4)));

DEV f4 ntl(const f4* p) { return __builtin_nontemporal_load(p); }

DEV float dot4(f4 w, f4 x) {
    float s = 0.f;
    s = fmaf(w.x, x.x, s); s = fmaf(w.y, x.y, s);
    s = fmaf(w.z, x.z, s); s = fmaf(w.w, x.w, s);
    return s;
}

DEV float wave_reduce(float v) {          // 64-lane sum -> lane 0
    for (int off = 32; off > 0; off >>= 1) v += __shfl_down(v, off);
    return v;
}
DEV float reduce32(float v) {             // sum within 32-lane group
    for (int off = 16; off > 0; off >>= 1) v += __shfl_xor(v, off);
    return v;
}

// ---- ws layout (float offsets, all %4==0) ----
#define WS_Q     0        // 1024  out_Q           (x_sigma = ws[0..1184))
#define WS_FC6   1024     // 160   relu(FC6@nd)
#define WS_SIG   1184     // 1024  out_Sigma
#define WS_FC1   2208     // 1024  out_FC1         (x_s = ws[2208..3552))
#define WS_FC7   3232     // 320   relu(FC7@[obs|innov])
#define WS_S     3552     // 1024  out_S
#define WS_HID   4576     // 81920 W1a @ sigma partials
#define WS_KG    86496    // 1024  KG accumulator (init b2, atomicAdd)
// total 87520 floats = 350,080 B

// ---- block-per-row GRU core: 256 threads compute one output element ----
template <int K4X>
DEV void gru_row(int row, int t, const float* __restrict__ x,
                 const float* __restrict__ h,
                 const float* __restrict__ Wih, const float* __restrict__ Whh,
                 const float* __restrict__ bih, const float* __restrict__ bhh,
                 float* __restrict__ out) {
    const f4* x4 = (const f4*)x;
    const f4* w0 = (const f4*)Wih + (size_t)row * K4X;
    const f4* w1 = (const f4*)Wih + (size_t)(1024 + row) * K4X;
    const f4* w2 = (const f4*)Wih + (size_t)(2048 + row) * K4X;
    float ai0 = 0.f, ai1 = 0.f, ai2 = 0.f;
    if (K4X >= 256 || t < K4X) {
        f4 xv = x4[t];
        ai0 = dot4(ntl(w0 + t), xv);
        ai1 = dot4(ntl(w1 + t), xv);
        ai2 = dot4(ntl(w2 + t), xv);
    }
    if (K4X > 256) {
        if (t < K4X - 256) {
            int k = 256 + t;
            f4 xv = x4[k];
            ai0 += dot4(ntl(w0 + k), xv);
            ai1 += dot4(ntl(w1 + k), xv);
            ai2 += dot4(ntl(w2 + k), xv);
        }
    }
    const f4* v0 = (const f4*)Whh + (size_t)row * 256;
    const f4* v1 = (const f4*)Whh + (size_t)(1024 + row) * 256;
    const f4* v2 = (const f4*)Whh + (size_t)(2048 + row) * 256;
    f4 hv = ((const f4*)h)[t];
    float ah0 = dot4(ntl(v0 + t), hv);
    float ah1 = dot4(ntl(v1 + t), hv);
    float ah2 = dot4(ntl(v2 + t), hv);
    ai0 = wave_reduce(ai0); ai1 = wave_reduce(ai1); ai2 = wave_reduce(ai2);
    ah0 = wave_reduce(ah0); ah1 = wave_reduce(ah1); ah2 = wave_reduce(ah2);
    __shared__ float red[4][6];
    int w = t >> 6, lane = t & 63;
    if (lane == 0) {
        red[w][0] = ai0; red[w][1] = ai1; red[w][2] = ai2;
        red[w][3] = ah0; red[w][4] = ah1; red[w][5] = ah2;
    }
    __syncthreads();
    if (t == 0) {
        float AI0 = red[0][0] + red[1][0] + red[2][0] + red[3][0];
        float AI1 = red[0][1] + red[1][1] + red[2][1] + red[3][1];
        float AI2 = red[0][2] + red[1][2] + red[2][2] + red[3][2];
        float AH0 = red[0][3] + red[1][3] + red[2][3] + red[3][3];
        float AH1 = red[0][4] + red[1][4] + red[2][4] + red[3][4];
        float AH2 = red[0][5] + red[1][5] + red[2][5] + red[3][5];
        float gr = AI0 + bih[row]        + AH0 + bhh[row];
        float gz = AI1 + bih[row + 1024] + AH1 + bhh[row + 1024];
        float r = 1.f / (1.f + expf(-gr));
        float z = 1.f / (1.f + expf(-gz));
        float n = tanhf(AI2 + bih[row + 2048] + r * (AH2 + bhh[row + 2048]));
        out[row] = (1.f - z) * n + z * h[row];
    }
}

// ---- K1: GRU_Q (blocks 0..1023) | FC6 (1024) | FC7+priors (1025) | KG=b2 init (1026..1029) ----
__global__ __launch_bounds__(256) void k_stage1(
        const float* __restrict__ y, const float* __restrict__ y_prev,
        const float* __restrict__ post, const float* __restrict__ post_prev,
        const float* __restrict__ prior_prev,
        const float* __restrict__ F, const float* __restrict__ Hm,
        const float* __restrict__ fc5w, const float* __restrict__ fc5b,
        const float* __restrict__ fc6w, const float* __restrict__ fc6b,
        const float* __restrict__ fc7w, const float* __restrict__ fc7b,
        const float* __restrict__ b2,
        const float* __restrict__ h_Q,
        const float* __restrict__ Wih, const float* __restrict__ Whh,
        const float* __restrict__ bih, const float* __restrict__ bhh,
        float* __restrict__ ws) {
    int t = threadIdx.x;
    if (blockIdx.x < 1024) {
        __shared__ __align__(16) float sx[160];
        __shared__ float sd[32];
        __shared__ float sinv;
        if (t < 32) sd[t] = post[t] - post_prev[t];
        __syncthreads();
        if (t < 64) {
            float d = (t < 32) ? sd[t] * sd[t] : 0.f;
            d = wave_reduce(d);
            if (t == 0) sinv = 1.f / fmaxf(sqrtf(d), 1e-12f);
        }
        __syncthreads();
        if (t < 160) {
            float a = 0.f;
#pragma unroll
            for (int j = 0; j < 32; ++j) a = fmaf(fc5w[t * 32 + j], sd[j], a);
            sx[t] = fmaxf(fmaf(a, sinv, fc5b[t]), 0.f);
        }
        __syncthreads();
        gru_row<40>(blockIdx.x, t, sx, h_Q, Wih, Whh, bih, bhh, ws + WS_Q);
    } else if (blockIdx.x == 1024) {
        __shared__ float sd[32];
        __shared__ float sinv;
        if (t < 32) sd[t] = post[t] - prior_prev[t];
        __syncthreads();
        if (t < 64) {
            float d = (t < 32) ? sd[t] * sd[t] : 0.f;
            d = wave_reduce(d);
            if (t == 0) sinv = 1.f / fmaxf(sqrtf(d), 1e-12f);
        }
        __syncthreads();
        if (t < 160) {
            float a = 0.f;
#pragma unroll
            for (int j = 0; j < 32; ++j) a = fmaf(fc6w[t * 32 + j], sd[j], a);
            ws[WS_FC6 + t] = fmaxf(fmaf(a, sinv, fc6b[t]), 0.f);
        }
    } else if (blockIdx.x == 1025) {
        __shared__ float sp[32], sd0[32], sd1[32];
        __shared__ float sinv0, sinv1;
        if (t < 32) {
            float p = 0.f;
#pragma unroll
            for (int j = 0; j < 32; ++j) p = fmaf(F[t * 32 + j], post[j], p);
            sp[t] = p;
            sd0[t] = y[t] - y_prev[t];
        }
        __syncthreads();
        if (t < 32) {
            float m = 0.f;
#pragma unroll
            for (int j = 0; j < 32; ++j) m = fmaf(Hm[t * 32 + j], sp[j], m);
            sd1[t] = y[t] - m;
        }
        __syncthreads();
        if (t < 64) {
            int g = t >> 5, j = t & 31;
            float d = g ? sd1[j] : sd0[j];
            float s = reduce32(d * d);
            if (j == 0) {
                float inv = 1.f / fmaxf(sqrtf(s), 1e-12f);
                if (g) sinv1 = inv; else sinv0 = inv;
            }
        }
        __syncthreads();
        for (int r = t; r < 320; r += 256) {
            float a0 = 0.f, a1 = 0.f;
#pragma unroll
            for (int j = 0; j < 32; ++j) {
                a0 = fmaf(fc7w[r * 64 + j], sd0[j], a0);
                a1 = fmaf(fc7w[r * 64 + 32 + j], sd1[j], a1);
            }
            ws[WS_FC7 + r] = fmaxf(a0 * sinv0 + a1 * sinv1 + fc7b[r], 0.f);
        }
    } else {
        int idx = ((blockIdx.x - 1026) << 8) + t;       // 0..1023
        ws[WS_KG + idx] = b2[idx];
    }
}

// ---- K2: GRU_Sigma, block-per-row, x = ws[0..1184) ----
__global__ __launch_bounds__(256) void k_stage2(
        const float* __restrict__ h, const float* __restrict__ Wih,
        const float* __restrict__ Whh, const float* __restrict__ bih,
        const float* __restrict__ bhh, float* __restrict__ ws) {
    gru_row<296>(blockIdx.x, threadIdx.x, ws + WS_Q, h, Wih, Whh, bih, bhh, ws + WS_SIG);
}

// ---- streaming W1a wave-per-row helper: partial = W1[wid, 0:1024] @ sigma ----
DEV void w1a_wave(int wid, int t, const float* __restrict__ W1, float* __restrict__ ws) {
    int lane = t & 63;
    const f4* w4 = (const f4*)W1 + (size_t)wid * 512;   // first 256 f4 = sigma cols
    const f4* x4 = (const f4*)(ws + WS_SIG);
    float a0 = 0.f, a1 = 0.f;
#pragma unroll
    for (int i = 0; i < 4; ++i) {
        int k = lane + (i << 6);
        float v = dot4(ntl(w4 + k), x4[k]);
        if (i & 1) a1 += v; else a0 += v;
    }
    float a = wave_reduce(a0 + a1);
    if (lane == 0) ws[WS_HID + wid] = a;
}

// ---- K3: FC1 (blocks 0..1023) | W1a rows 0..40959 ----
__global__ __launch_bounds__(256) void k_stage3(
        const float* __restrict__ W1, const float* __restrict__ fc1w,
        const float* __restrict__ fc1b, float* __restrict__ ws) {
    int t = threadIdx.x;
    if (blockIdx.x < 1024) {
        int row = blockIdx.x;
        const f4* w4 = (const f4*)fc1w + (size_t)row * 256;
        const f4* x4 = (const f4*)(ws + WS_SIG);
        float a = dot4(ntl(w4 + t), x4[t]);
        a = wave_reduce(a);
        __shared__ float s[4];
        if ((t & 63) == 0) s[t >> 6] = a;
        __syncthreads();
        if (t == 0) ws[WS_FC1 + row] = fmaxf(s[0] + s[1] + s[2] + s[3] + fc1b[row], 0.f);
    } else {
        int wid = ((blockIdx.x - 1024) << 2) + (t >> 6);        // 0..40959
        w1a_wave(wid, t, W1, ws);
    }
}

// ---- K4: GRU_S (blocks 0..1023) | W1a rows 40960..81919 ----
__global__ __launch_bounds__(256) void k_stage4(
        const float* __restrict__ W1, const float* __restrict__ h,
        const float* __restrict__ Wih, const float* __restrict__ Whh,
        const float* __restrict__ bih, const float* __restrict__ bhh,
        float* __restrict__ ws) {
    int t = threadIdx.x;
    if (blockIdx.x < 1024) {
        gru_row<336>(blockIdx.x, t, ws + WS_FC1, h, Wih, Whh, bih, bhh, ws + WS_S);
    } else {
        int wid = 40960 + ((blockIdx.x - 1024) << 2) + (t >> 6);
        w1a_wave(wid, t, W1, ws);
    }
}

// ---- K5 (fused W1b + W2): per block, 160 hidden cols:
//      hid_c = relu(partial_c + W1[c,1024:2048]@S + b1_c)  -> LDS
//      KG   += W2[:, chunk] @ hid_chunk                    (atomicAdd)
__global__ __launch_bounds__(512) void k_fc2_fused(
        const float* __restrict__ W1, const float* __restrict__ b1,
        const float* __restrict__ W2, float* __restrict__ ws) {
    __shared__ __align__(16) float shid[160];
    int t = threadIdx.x;
    int w = t >> 6, lane = t & 63;
    int c0 = blockIdx.x * 160;
    const f4* xS = (const f4*)(ws + WS_S);
    // step 1: finalize 160 hid values (wave-per-col, 20 cols per wave)
    for (int c = w; c < 160; c += 8) {
        int row = c0 + c;
        const f4* wr = (const f4*)W1 + (size_t)row * 512 + 256;   // cols 1024..2047
        float a0 = 0.f, a1 = 0.f;
#pragma unroll
        for (int i = 0; i < 4; ++i) {
            int k = lane + (i << 6);
            float v = dot4(ntl(wr + k), xS[k]);
            if (i & 1) a1 += v; else a0 += v;
        }
        float a = wave_reduce(a0 + a1);
        if (lane == 0) shid[c] = fmaxf(ws[WS_HID + row] + a + b1[row], 0.f);
    }
    __syncthreads();
    // step 2: rank-160 update of KG (wave-per-row, 128 rows per wave)
    const f4* sh4 = (const f4*)shid;          // 40 f4
    f4 hv = (lane < 40) ? sh4[lane] : f4{0.f, 0.f, 0.f, 0.f};
    const f4* w2base = (const f4*)W2 + blockIdx.x * 40;
#pragma unroll 2
    for (int k = 0; k < 128; ++k) {
        int r = w + (k << 3);
        float a = 0.f;
        if (lane < 40) a = dot4(ntl(w2base + (size_t)r * 20480 + lane), hv);
        a = wave_reduce(a);
        if (lane == 0) atomicAdd(&ws[WS_KG + r], a);
    }
}

// ---- K6: out = prior + KG @ (y - H@prior) ----
__global__ void k_final(const float* __restrict__ F, const float* __restrict__ Hm,
                        const float* __restrict__ post, const float* __restrict__ y,
                        const float* __restrict__ kg, float* __restrict__ out) {
    __shared__ float sprior[32], sdy[32];
    int i = threadIdx.x;   // 32
    float p = 0.f;
#pragma unroll
    for (int j = 0; j < 32; ++j) p = fmaf(F[i * 32 + j], post[j], p);
    sprior[i] = p;
    __syncthreads();
    float m = 0.f;
#pragma unroll
    for (int j = 0; j < 32; ++j) m = fmaf(Hm[i * 32 + j], sprior[j], m);
    sdy[i] = y[i] - m;
    __syncthreads();
    float a = sprior[i];
#pragma unroll
    for (int j = 0; j < 32; ++j) a = fmaf(kg[i * 32 + j], sdy[j], a);
    out[i] = a;
}

extern "C" void kernel_launch(void* const* d_in, const int* in_sizes, int n_in,
                              void* d_out, int out_size, void* d_ws, size_t ws_size,
                              hipStream_t stream) {
    const float* y          = (const float*)d_in[0];
    const float* post       = (const float*)d_in[1];
    const float* post_prev  = (const float*)d_in[2];
    const float* prior_prev = (const float*)d_in[3];
    const float* y_prev     = (const float*)d_in[4];
    const float* h_Q        = (const float*)d_in[5];
    const float* h_Sigma    = (const float*)d_in[6];
    const float* h_S        = (const float*)d_in[7];
    const float* F          = (const float*)d_in[8];
    const float* Hm         = (const float*)d_in[9];
    const float* FC5_w      = (const float*)d_in[10];
    const float* FC5_b      = (const float*)d_in[11];
    const float* FC6_w      = (const float*)d_in[12];
    const float* FC6_b      = (const float*)d_in[13];
    const float* FC7_w      = (const float*)d_in[14];
    const float* FC7_b      = (const float*)d_in[15];
    const float* GQ_Wih     = (const float*)d_in[16];
    const float* GQ_Whh     = (const float*)d_in[17];
    const float* GQ_bih     = (const float*)d_in[18];
    const float* GQ_bhh     = (const float*)d_in[19];
    const float* GS_Wih     = (const float*)d_in[20];
    const float* GS_Whh     = (const float*)d_in[21];
    const float* GS_bih     = (const float*)d_in[22];
    const float* GS_bhh     = (const float*)d_in[23];
    const float* GU_Wih     = (const float*)d_in[24];
    const float* GU_Whh     = (const float*)d_in[25];
    const float* GU_bih     = (const float*)d_in[26];
    const float* GU_bhh     = (const float*)d_in[27];
    const float* FC1_w      = (const float*)d_in[28];
    const float* FC1_b      = (const float*)d_in[29];
    const float* FC2_w1     = (const float*)d_in[30];
    const float* FC2_b1     = (const float*)d_in[31];
    const float* FC2_w2     = (const float*)d_in[32];
    const float* FC2_b2     = (const float*)d_in[33];
    // d_in[34..37] = FC3/FC4 (dead); d_in[38] = fix_H_flag (always 1)

    float* ws = (float*)d_ws;

    // K1: GRU_Q | FC6 | FC7(+priors) | KG=b2
    k_stage1<<<1030, 256, 0, stream>>>(y, y_prev, post, post_prev, prior_prev, F, Hm,
                                       FC5_w, FC5_b, FC6_w, FC6_b, FC7_w, FC7_b, FC2_b2,
                                       h_Q, GQ_Wih, GQ_Whh, GQ_bih, GQ_bhh, ws);
    // K2: GRU_Sigma
    k_stage2<<<1024, 256, 0, stream>>>(h_Sigma, GS_Wih, GS_Whh, GS_bih, GS_bhh, ws);
    // K3: FC1 || W1a rows 0..40959
    k_stage3<<<11264, 256, 0, stream>>>(FC2_w1, FC1_w, FC1_b, ws);
    // K4: GRU_S || W1a rows 40960..81919
    k_stage4<<<11264, 256, 0, stream>>>(FC2_w1, h_S, GU_Wih, GU_Whh, GU_bih, GU_bhh, ws);
    // K5: fused W1b + W2 -> KG (atomic accumulate)
    k_fc2_fused<<<512, 512, 0, stream>>>(FC2_w1, FC2_b1, FC2_w2, ws);
    // K6: epilogue
    k_final<<<1, 32, 0, stream>>>(F, Hm, post, y, ws + WS_KG, (float*)d_out);
}

// Round 6
// 181.049 us; speedup vs baseline: 3.9660x; 3.9660x over previous
//
#include <hip/hip_runtime.h>
#include <math.h>

#define DEV __device__ __forceinline__

typedef float f4 __attribute__((ext_vector_type(4)));

DEV f4 ntl(const f4* p) { return __builtin_nontemporal_load(p); }

DEV float dot4(f4 w, f4 x) {
    float s = 0.f;
    s = fmaf(w.x, x.x, s); s = fmaf(w.y, x.y, s);
    s = fmaf(w.z, x.z, s); s = fmaf(w.w, x.w, s);
    return s;
}

DEV float wave_reduce(float v) {          // 64-lane sum -> lane 0
    for (int off = 32; off > 0; off >>= 1) v += __shfl_down(v, off);
    return v;
}
DEV float reduce32(float v) {             // sum within 32-lane group
    for (int off = 16; off > 0; off >>= 1) v += __shfl_xor(v, off);
    return v;
}

// ---- ws layout (float offsets, all %4==0) ----
#define WS_Q     0        // 1024  out_Q           (x_sigma = ws[0..1184))
#define WS_FC6   1024     // 160   relu(FC6@nd)
#define WS_SIG   1184     // 1024  out_Sigma
#define WS_FC1   2208     // 1024  out_FC1         (x_s = ws[2208..3552))
#define WS_FC7   3232     // 320   relu(FC7@[obs|innov])
#define WS_S     3552     // 1024  out_S
#define WS_HID   4576     // 81920 W1a @ sigma partials
#define WS_DY    86496    // 32    dy = y - H@prior
// total 86528 floats = 346,112 B

// ---- block-per-row GRU core: 256 threads compute one output element ----
template <int K4X>
DEV void gru_row(int row, int t, const float* __restrict__ x,
                 const float* __restrict__ h,
                 const float* __restrict__ Wih, const float* __restrict__ Whh,
                 const float* __restrict__ bih, const float* __restrict__ bhh,
                 float* __restrict__ out) {
    const f4* x4 = (const f4*)x;
    const f4* w0 = (const f4*)Wih + (size_t)row * K4X;
    const f4* w1 = (const f4*)Wih + (size_t)(1024 + row) * K4X;
    const f4* w2 = (const f4*)Wih + (size_t)(2048 + row) * K4X;
    float ai0 = 0.f, ai1 = 0.f, ai2 = 0.f;
    if (K4X >= 256 || t < K4X) {
        f4 xv = x4[t];
        ai0 = dot4(ntl(w0 + t), xv);
        ai1 = dot4(ntl(w1 + t), xv);
        ai2 = dot4(ntl(w2 + t), xv);
    }
    if (K4X > 256) {
        if (t < K4X - 256) {
            int k = 256 + t;
            f4 xv = x4[k];
            ai0 += dot4(ntl(w0 + k), xv);
            ai1 += dot4(ntl(w1 + k), xv);
            ai2 += dot4(ntl(w2 + k), xv);
        }
    }
    const f4* v0 = (const f4*)Whh + (size_t)row * 256;
    const f4* v1 = (const f4*)Whh + (size_t)(1024 + row) * 256;
    const f4* v2 = (const f4*)Whh + (size_t)(2048 + row) * 256;
    f4 hv = ((const f4*)h)[t];
    float ah0 = dot4(ntl(v0 + t), hv);
    float ah1 = dot4(ntl(v1 + t), hv);
    float ah2 = dot4(ntl(v2 + t), hv);
    ai0 = wave_reduce(ai0); ai1 = wave_reduce(ai1); ai2 = wave_reduce(ai2);
    ah0 = wave_reduce(ah0); ah1 = wave_reduce(ah1); ah2 = wave_reduce(ah2);
    __shared__ float red[4][6];
    int w = t >> 6, lane = t & 63;
    if (lane == 0) {
        red[w][0] = ai0; red[w][1] = ai1; red[w][2] = ai2;
        red[w][3] = ah0; red[w][4] = ah1; red[w][5] = ah2;
    }
    __syncthreads();
    if (t == 0) {
        float AI0 = red[0][0] + red[1][0] + red[2][0] + red[3][0];
        float AI1 = red[0][1] + red[1][1] + red[2][1] + red[3][1];
        float AI2 = red[0][2] + red[1][2] + red[2][2] + red[3][2];
        float AH0 = red[0][3] + red[1][3] + red[2][3] + red[3][3];
        float AH1 = red[0][4] + red[1][4] + red[2][4] + red[3][4];
        float AH2 = red[0][5] + red[1][5] + red[2][5] + red[3][5];
        float gr = AI0 + bih[row]        + AH0 + bhh[row];
        float gz = AI1 + bih[row + 1024] + AH1 + bhh[row + 1024];
        float r = 1.f / (1.f + expf(-gr));
        float z = 1.f / (1.f + expf(-gz));
        float n = tanhf(AI2 + bih[row + 2048] + r * (AH2 + bhh[row + 2048]));
        out[row] = (1.f - z) * n + z * h[row];
    }
}

// ---- K1: GRU_Q (blocks 0..1023) | FC6 (1024) | FC7 + priors + dy + out-init (1025) ----
__global__ __launch_bounds__(256) void k_stage1(
        const float* __restrict__ y, const float* __restrict__ y_prev,
        const float* __restrict__ post, const float* __restrict__ post_prev,
        const float* __restrict__ prior_prev,
        const float* __restrict__ F, const float* __restrict__ Hm,
        const float* __restrict__ fc5w, const float* __restrict__ fc5b,
        const float* __restrict__ fc6w, const float* __restrict__ fc6b,
        const float* __restrict__ fc7w, const float* __restrict__ fc7b,
        const float* __restrict__ h_Q,
        const float* __restrict__ Wih, const float* __restrict__ Whh,
        const float* __restrict__ bih, const float* __restrict__ bhh,
        float* __restrict__ ws, float* __restrict__ out) {
    int t = threadIdx.x;
    if (blockIdx.x < 1024) {
        __shared__ __align__(16) float sx[160];
        __shared__ float sd[32];
        __shared__ float sinv;
        if (t < 32) sd[t] = post[t] - post_prev[t];
        __syncthreads();
        if (t < 64) {
            float d = (t < 32) ? sd[t] * sd[t] : 0.f;
            d = wave_reduce(d);
            if (t == 0) sinv = 1.f / fmaxf(sqrtf(d), 1e-12f);
        }
        __syncthreads();
        if (t < 160) {
            float a = 0.f;
#pragma unroll
            for (int j = 0; j < 32; ++j) a = fmaf(fc5w[t * 32 + j], sd[j], a);
            sx[t] = fmaxf(fmaf(a, sinv, fc5b[t]), 0.f);
        }
        __syncthreads();
        gru_row<40>(blockIdx.x, t, sx, h_Q, Wih, Whh, bih, bhh, ws + WS_Q);
    } else if (blockIdx.x == 1024) {
        __shared__ float sd[32];
        __shared__ float sinv;
        if (t < 32) sd[t] = post[t] - prior_prev[t];
        __syncthreads();
        if (t < 64) {
            float d = (t < 32) ? sd[t] * sd[t] : 0.f;
            d = wave_reduce(d);
            if (t == 0) sinv = 1.f / fmaxf(sqrtf(d), 1e-12f);
        }
        __syncthreads();
        if (t < 160) {
            float a = 0.f;
#pragma unroll
            for (int j = 0; j < 32; ++j) a = fmaf(fc6w[t * 32 + j], sd[j], a);
            ws[WS_FC6 + t] = fmaxf(fmaf(a, sinv, fc6b[t]), 0.f);
        }
    } else {
        __shared__ float sp[32], sd0[32], sd1[32];
        __shared__ float sinv0, sinv1;
        if (t < 32) {
            float p = 0.f;
#pragma unroll
            for (int j = 0; j < 32; ++j) p = fmaf(F[t * 32 + j], post[j], p);
            sp[t] = p;
            sd0[t] = y[t] - y_prev[t];
        }
        __syncthreads();
        if (t < 32) {
            float m = 0.f;
#pragma unroll
            for (int j = 0; j < 32; ++j) m = fmaf(Hm[t * 32 + j], sp[j], m);
            float dy = y[t] - m;
            sd1[t] = dy;
            ws[WS_DY + t] = dy;
            out[t] = sp[t];              // out starts as m1x_prior; k_w2 accumulates KG@dy
        }
        __syncthreads();
        if (t < 64) {
            int g = t >> 5, j = t & 31;
            float d = g ? sd1[j] : sd0[j];
            float s = reduce32(d * d);
            if (j == 0) {
                float inv = 1.f / fmaxf(sqrtf(s), 1e-12f);
                if (g) sinv1 = inv; else sinv0 = inv;
            }
        }
        __syncthreads();
        for (int r = t; r < 320; r += 256) {
            float a0 = 0.f, a1 = 0.f;
#pragma unroll
            for (int j = 0; j < 32; ++j) {
                a0 = fmaf(fc7w[r * 64 + j], sd0[j], a0);
                a1 = fmaf(fc7w[r * 64 + 32 + j], sd1[j], a1);
            }
            ws[WS_FC7 + r] = fmaxf(a0 * sinv0 + a1 * sinv1 + fc7b[r], 0.f);
        }
    }
}

// ---- K2: GRU_Sigma, block-per-row, x = ws[0..1184) ----
__global__ __launch_bounds__(256) void k_stage2(
        const float* __restrict__ h, const float* __restrict__ Wih,
        const float* __restrict__ Whh, const float* __restrict__ bih,
        const float* __restrict__ bhh, float* __restrict__ ws) {
    gru_row<296>(blockIdx.x, threadIdx.x, ws + WS_Q, h, Wih, Whh, bih, bhh, ws + WS_SIG);
}

// ---- streaming W1a wave-per-row helper: partial = W1[wid, 0:1024] @ sigma ----
DEV void w1a_wave(int wid, int t, const float* __restrict__ W1, float* __restrict__ ws) {
    int lane = t & 63;
    const f4* w4 = (const f4*)W1 + (size_t)wid * 512;   // first 256 f4 = sigma cols
    const f4* x4 = (const f4*)(ws + WS_SIG);
    float a0 = 0.f, a1 = 0.f;
#pragma unroll
    for (int i = 0; i < 4; ++i) {
        int k = lane + (i << 6);
        float v = dot4(ntl(w4 + k), x4[k]);
        if (i & 1) a1 += v; else a0 += v;
    }
    float a = wave_reduce(a0 + a1);
    if (lane == 0) ws[WS_HID + wid] = a;
}

// ---- K3: FC1 (blocks 0..1023) | W1a rows 0..40959 ----
__global__ __launch_bounds__(256) void k_stage3(
        const float* __restrict__ W1, const float* __restrict__ fc1w,
        const float* __restrict__ fc1b, float* __restrict__ ws) {
    int t = threadIdx.x;
    if (blockIdx.x < 1024) {
        int row = blockIdx.x;
        const f4* w4 = (const f4*)fc1w + (size_t)row * 256;
        const f4* x4 = (const f4*)(ws + WS_SIG);
        float a = dot4(ntl(w4 + t), x4[t]);
        a = wave_reduce(a);
        __shared__ float s[4];
        if ((t & 63) == 0) s[t >> 6] = a;
        __syncthreads();
        if (t == 0) ws[WS_FC1 + row] = fmaxf(s[0] + s[1] + s[2] + s[3] + fc1b[row], 0.f);
    } else {
        int wid = ((blockIdx.x - 1024) << 2) + (t >> 6);        // 0..40959
        w1a_wave(wid, t, W1, ws);
    }
}

// ---- K4: GRU_S (blocks 0..1023) | W1a rows 40960..81919 ----
__global__ __launch_bounds__(256) void k_stage4(
        const float* __restrict__ W1, const float* __restrict__ h,
        const float* __restrict__ Wih, const float* __restrict__ Whh,
        const float* __restrict__ bih, const float* __restrict__ bhh,
        float* __restrict__ ws) {
    int t = threadIdx.x;
    if (blockIdx.x < 1024) {
        gru_row<336>(blockIdx.x, t, ws + WS_FC1, h, Wih, Whh, bih, bhh, ws + WS_S);
    } else {
        int wid = 40960 + ((blockIdx.x - 1024) << 2) + (t >> 6);
        w1a_wave(wid, t, W1, ws);
    }
}

// ---- K5: hid = relu(partial + W1[:,1024:2048] @ out_S + b1) ----
__global__ __launch_bounds__(256) void k_w1b(
        const float* __restrict__ W1, const float* __restrict__ b1,
        float* __restrict__ ws) {
    int wid = (blockIdx.x << 2) + (threadIdx.x >> 6);
    int lane = threadIdx.x & 63;
    const f4* w4 = (const f4*)W1 + (size_t)wid * 512 + 256;     // cols 1024..2047
    const f4* x4 = (const f4*)(ws + WS_S);
    float a0 = 0.f, a1 = 0.f;
#pragma unroll
    for (int i = 0; i < 4; ++i) {
        int k = lane + (i << 6);
        float v = dot4(ntl(w4 + k), x4[k]);
        if (i & 1) a1 += v; else a0 += v;
    }
    float a = wave_reduce(a0 + a1);
    if (lane == 0) ws[WS_HID + wid] = fmaxf(ws[WS_HID + wid] + a + b1[wid], 0.f);
}

// ---- K6: KG[row] = W2[row] @ hid + b2[row]; out[row>>5] += KG[row] * dy[row&31] ----
__global__ __launch_bounds__(512) void k_w2(
        const float* __restrict__ W2, const float* __restrict__ b2,
        const float* __restrict__ ws, float* __restrict__ out) {
    int row = blockIdx.x;
    int t = threadIdx.x;
    const f4* w4 = (const f4*)W2 + (size_t)row * 20480;
    const f4* x4 = (const f4*)(ws + WS_HID);
    float a0 = 0.f, a1 = 0.f;
#pragma unroll 4
    for (int k = t; k < 20480; k += 512) {
        float v = dot4(ntl(w4 + k), x4[k]);
        if (k & 512) a1 += v; else a0 += v;
    }
    float a = wave_reduce(a0 + a1);
    __shared__ float s[8];
    if ((t & 63) == 0) s[t >> 6] = a;
    __syncthreads();
    if (t == 0) {
        float r = b2[row];
#pragma unroll
        for (int i = 0; i < 8; ++i) r += s[i];
        atomicAdd(&out[row >> 5], r * ws[WS_DY + (row & 31)]);
    }
}

extern "C" void kernel_launch(void* const* d_in, const int* in_sizes, int n_in,
                              void* d_out, int out_size, void* d_ws, size_t ws_size,
                              hipStream_t stream) {
    const float* y          = (const float*)d_in[0];
    const float* post       = (const float*)d_in[1];
    const float* post_prev  = (const float*)d_in[2];
    const float* prior_prev = (const float*)d_in[3];
    const float* y_prev     = (const float*)d_in[4];
    const float* h_Q        = (const float*)d_in[5];
    const float* h_Sigma    = (const float*)d_in[6];
    const float* h_S        = (const float*)d_in[7];
    const float* F          = (const float*)d_in[8];
    const float* Hm         = (const float*)d_in[9];
    const float* FC5_w      = (const float*)d_in[10];
    const float* FC5_b      = (const float*)d_in[11];
    const float* FC6_w      = (const float*)d_in[12];
    const float* FC6_b      = (const float*)d_in[13];
    const float* FC7_w      = (const float*)d_in[14];
    const float* FC7_b      = (const float*)d_in[15];
    const float* GQ_Wih     = (const float*)d_in[16];
    const float* GQ_Whh     = (const float*)d_in[17];
    const float* GQ_bih     = (const float*)d_in[18];
    const float* GQ_bhh     = (const float*)d_in[19];
    const float* GS_Wih     = (const float*)d_in[20];
    const float* GS_Whh     = (const float*)d_in[21];
    const float* GS_bih     = (const float*)d_in[22];
    const float* GS_bhh     = (const float*)d_in[23];
    const float* GU_Wih     = (const float*)d_in[24];
    const float* GU_Whh     = (const float*)d_in[25];
    const float* GU_bih     = (const float*)d_in[26];
    const float* GU_bhh     = (const float*)d_in[27];
    const float* FC1_w      = (const float*)d_in[28];
    const float* FC1_b      = (const float*)d_in[29];
    const float* FC2_w1     = (const float*)d_in[30];
    const float* FC2_b1     = (const float*)d_in[31];
    const float* FC2_w2     = (const float*)d_in[32];
    const float* FC2_b2     = (const float*)d_in[33];
    // d_in[34..37] = FC3/FC4 (dead); d_in[38] = fix_H_flag (always 1)

    float* ws = (float*)d_ws;
    float* out = (float*)d_out;

    // K1: GRU_Q | FC6 | FC7(+priors, dy, out=prior)
    k_stage1<<<1026, 256, 0, stream>>>(y, y_prev, post, post_prev, prior_prev, F, Hm,
                                       FC5_w, FC5_b, FC6_w, FC6_b, FC7_w, FC7_b,
                                       h_Q, GQ_Wih, GQ_Whh, GQ_bih, GQ_bhh, ws, out);
    // K2: GRU_Sigma
    k_stage2<<<1024, 256, 0, stream>>>(h_Sigma, GS_Wih, GS_Whh, GS_bih, GS_bhh, ws);
    // K3: FC1 || W1a rows 0..40959
    k_stage3<<<11264, 256, 0, stream>>>(FC2_w1, FC1_w, FC1_b, ws);
    // K4: GRU_S || W1a rows 40960..81919
    k_stage4<<<11264, 256, 0, stream>>>(FC2_w1, h_S, GU_Wih, GU_Whh, GU_bih, GU_bhh, ws);
    // K5: hid = relu(partial + W1b @ out_S + b1)
    k_w1b<<<20480, 256, 0, stream>>>(FC2_w1, FC2_b1, ws);
    // K6: KG row + fused epilogue (atomicAdd into out)
    k_w2<<<1024, 512, 0, stream>>>(FC2_w2, FC2_b2, ws, out);
}

// Round 7
// 179.912 us; speedup vs baseline: 3.9911x; 1.0063x over previous
//
#include <hip/hip_runtime.h>
#include <math.h>

#define DEV __device__ __forceinline__

typedef float f4 __attribute__((ext_vector_type(4)));

DEV f4 ntl(const f4* p) { return __builtin_nontemporal_load(p); }

DEV float dot4(f4 w, f4 x) {
    float s = 0.f;
    s = fmaf(w.x, x.x, s); s = fmaf(w.y, x.y, s);
    s = fmaf(w.z, x.z, s); s = fmaf(w.w, x.w, s);
    return s;
}

DEV float wave_reduce(float v) {          // 64-lane sum -> lane 0
    for (int off = 32; off > 0; off >>= 1) v += __shfl_down(v, off);
    return v;
}
DEV float reduce32(float v) {             // sum within 32-lane group
    for (int off = 16; off > 0; off >>= 1) v += __shfl_xor(v, off);
    return v;
}

// ---- ws layout (float offsets, all %4==0) ----
#define WS_Q     0        // 1024  out_Q          (x_sigma = ws[0..1184))
#define WS_FC6   1024     // 160   relu(FC6@nd)
#define WS_SIG   1184     // 1024  out_Sigma
#define WS_FC1   2208     // 1024  out_FC1
#define WS_FC7   3232     // 320   relu(FC7@[obs|innov])
#define WS_S     3552     // 1024  out_S
#define WS_AHS   4576     // 3072  GRU_Sigma Whh@h gate sums (3 arrays of 1024)
#define WS_AHU   7648     // 3072  GRU_S     Whh@h gate sums
#define WS_AIU   10720    // 3072  GRU_S Wih[:,FC7-cols]@fc7 gate partials
#define WS_HID   13792    // 81920 W1a @ sigma partials -> relu'd hid
#define WS_DY    95712    // 32    dy = y - H@prior
// total 95744 floats = 382,976 B

// ---- full GRU row (Wih + Whh streamed): used for GRU_Q only ----
template <int K4X>
DEV void gru_row(int row, int t, const float* __restrict__ x,
                 const float* __restrict__ h,
                 const float* __restrict__ Wih, const float* __restrict__ Whh,
                 const float* __restrict__ bih, const float* __restrict__ bhh,
                 float* __restrict__ out) {
    const f4* x4 = (const f4*)x;
    const f4* w0 = (const f4*)Wih + (size_t)row * K4X;
    const f4* w1 = (const f4*)Wih + (size_t)(1024 + row) * K4X;
    const f4* w2 = (const f4*)Wih + (size_t)(2048 + row) * K4X;
    float ai0 = 0.f, ai1 = 0.f, ai2 = 0.f;
    if (K4X >= 256 || t < K4X) {
        f4 xv = x4[t];
        ai0 = dot4(ntl(w0 + t), xv);
        ai1 = dot4(ntl(w1 + t), xv);
        ai2 = dot4(ntl(w2 + t), xv);
    }
    const f4* v0 = (const f4*)Whh + (size_t)row * 256;
    const f4* v1 = (const f4*)Whh + (size_t)(1024 + row) * 256;
    const f4* v2 = (const f4*)Whh + (size_t)(2048 + row) * 256;
    f4 hv = ((const f4*)h)[t];
    float ah0 = dot4(ntl(v0 + t), hv);
    float ah1 = dot4(ntl(v1 + t), hv);
    float ah2 = dot4(ntl(v2 + t), hv);
    ai0 = wave_reduce(ai0); ai1 = wave_reduce(ai1); ai2 = wave_reduce(ai2);
    ah0 = wave_reduce(ah0); ah1 = wave_reduce(ah1); ah2 = wave_reduce(ah2);
    __shared__ float red[4][6];
    int w = t >> 6, lane = t & 63;
    if (lane == 0) {
        red[w][0] = ai0; red[w][1] = ai1; red[w][2] = ai2;
        red[w][3] = ah0; red[w][4] = ah1; red[w][5] = ah2;
    }
    __syncthreads();
    if (t == 0) {
        float AI0 = red[0][0] + red[1][0] + red[2][0] + red[3][0];
        float AI1 = red[0][1] + red[1][1] + red[2][1] + red[3][1];
        float AI2 = red[0][2] + red[1][2] + red[2][2] + red[3][2];
        float AH0 = red[0][3] + red[1][3] + red[2][3] + red[3][3];
        float AH1 = red[0][4] + red[1][4] + red[2][4] + red[3][4];
        float AH2 = red[0][5] + red[1][5] + red[2][5] + red[3][5];
        float gr = AI0 + bih[row]        + AH0 + bhh[row];
        float gz = AI1 + bih[row + 1024] + AH1 + bhh[row + 1024];
        float r = 1.f / (1.f + expf(-gr));
        float z = 1.f / (1.f + expf(-gz));
        float n = tanhf(AI2 + bih[row + 2048] + r * (AH2 + bhh[row + 2048]));
        out[row] = (1.f - z) * n + z * h[row];
    }
}

// ---- h-side gate sums for one row: dst_g[row] = Whh[g*1024+row] @ h ----
DEV void hh_row(int row, int t, const float* __restrict__ h,
                const float* __restrict__ Whh, float* __restrict__ dst) {
    const f4* v0 = (const f4*)Whh + (size_t)row * 256;
    const f4* v1 = (const f4*)Whh + (size_t)(1024 + row) * 256;
    const f4* v2 = (const f4*)Whh + (size_t)(2048 + row) * 256;
    f4 hv = ((const f4*)h)[t];
    float a0 = dot4(ntl(v0 + t), hv);
    float a1 = dot4(ntl(v1 + t), hv);
    float a2 = dot4(ntl(v2 + t), hv);
    a0 = wave_reduce(a0); a1 = wave_reduce(a1); a2 = wave_reduce(a2);
    __shared__ float red[4][3];
    int w = t >> 6, lane = t & 63;
    if (lane == 0) { red[w][0] = a0; red[w][1] = a1; red[w][2] = a2; }
    __syncthreads();
    if (t == 0) {
        dst[row]        = red[0][0] + red[1][0] + red[2][0] + red[3][0];
        dst[row + 1024] = red[0][1] + red[1][1] + red[2][1] + red[3][1];
        dst[row + 2048] = red[0][2] + red[1][2] + red[2][2] + red[3][2];
    }
}

// ---- K1: GRU_Q (0..1023) | FC6 (1024) | FC7+priors+dy+out-init (1025)
//         | Sigma-hh (1026..2049) | S-hh (2050..3073) ----
__global__ __launch_bounds__(256) void k_stage1(
        const float* __restrict__ y, const float* __restrict__ y_prev,
        const float* __restrict__ post, const float* __restrict__ post_prev,
        const float* __restrict__ prior_prev,
        const float* __restrict__ F, const float* __restrict__ Hm,
        const float* __restrict__ fc5w, const float* __restrict__ fc5b,
        const float* __restrict__ fc6w, const float* __restrict__ fc6b,
        const float* __restrict__ fc7w, const float* __restrict__ fc7b,
        const float* __restrict__ h_Q, const float* __restrict__ h_Sig,
        const float* __restrict__ h_S,
        const float* __restrict__ Wih, const float* __restrict__ Whh,
        const float* __restrict__ bih, const float* __restrict__ bhh,
        const float* __restrict__ WhhSig, const float* __restrict__ WhhS,
        float* __restrict__ ws, float* __restrict__ out) {
    int t = threadIdx.x;
    int b = blockIdx.x;
    if (b < 1024) {
        __shared__ __align__(16) float sx[160];
        __shared__ float sd[32];
        __shared__ float sinv;
        if (t < 32) sd[t] = post[t] - post_prev[t];
        __syncthreads();
        if (t < 64) {
            float d = (t < 32) ? sd[t] * sd[t] : 0.f;
            d = wave_reduce(d);
            if (t == 0) sinv = 1.f / fmaxf(sqrtf(d), 1e-12f);
        }
        __syncthreads();
        if (t < 160) {
            float a = 0.f;
#pragma unroll
            for (int j = 0; j < 32; ++j) a = fmaf(fc5w[t * 32 + j], sd[j], a);
            sx[t] = fmaxf(fmaf(a, sinv, fc5b[t]), 0.f);
        }
        __syncthreads();
        gru_row<40>(b, t, sx, h_Q, Wih, Whh, bih, bhh, ws + WS_Q);
    } else if (b == 1024) {
        __shared__ float sd[32];
        __shared__ float sinv;
        if (t < 32) sd[t] = post[t] - prior_prev[t];
        __syncthreads();
        if (t < 64) {
            float d = (t < 32) ? sd[t] * sd[t] : 0.f;
            d = wave_reduce(d);
            if (t == 0) sinv = 1.f / fmaxf(sqrtf(d), 1e-12f);
        }
        __syncthreads();
        if (t < 160) {
            float a = 0.f;
#pragma unroll
            for (int j = 0; j < 32; ++j) a = fmaf(fc6w[t * 32 + j], sd[j], a);
            ws[WS_FC6 + t] = fmaxf(fmaf(a, sinv, fc6b[t]), 0.f);
        }
    } else if (b == 1025) {
        __shared__ float sp[32], sd0[32], sd1[32];
        __shared__ float sinv0, sinv1;
        if (t < 32) {
            float p = 0.f;
#pragma unroll
            for (int j = 0; j < 32; ++j) p = fmaf(F[t * 32 + j], post[j], p);
            sp[t] = p;
            sd0[t] = y[t] - y_prev[t];
        }
        __syncthreads();
        if (t < 32) {
            float m = 0.f;
#pragma unroll
            for (int j = 0; j < 32; ++j) m = fmaf(Hm[t * 32 + j], sp[j], m);
            float dy = y[t] - m;
            sd1[t] = dy;
            ws[WS_DY + t] = dy;
            out[t] = sp[t];          // out = m1x_prior; k_w2 accumulates KG@dy
        }
        __syncthreads();
        if (t < 64) {
            int g = t >> 5, j = t & 31;
            float d = g ? sd1[j] : sd0[j];
            float s = reduce32(d * d);
            if (j == 0) {
                float inv = 1.f / fmaxf(sqrtf(s), 1e-12f);
                if (g) sinv1 = inv; else sinv0 = inv;
            }
        }
        __syncthreads();
        for (int r = t; r < 320; r += 256) {
            float a0 = 0.f, a1 = 0.f;
#pragma unroll
            for (int j = 0; j < 32; ++j) {
                a0 = fmaf(fc7w[r * 64 + j], sd0[j], a0);
                a1 = fmaf(fc7w[r * 64 + 32 + j], sd1[j], a1);
            }
            ws[WS_FC7 + r] = fmaxf(a0 * sinv0 + a1 * sinv1 + fc7b[r], 0.f);
        }
    } else if (b < 2050) {
        hh_row(b - 1026, t, h_Sig, WhhSig, ws + WS_AHS);
    } else {
        hh_row(b - 2050, t, h_S, WhhS, ws + WS_AHU);
    }
}

// ---- K2: GRU_Sigma, Wih-only (Whh gate sums precomputed in K1) ----
__global__ __launch_bounds__(256) void k_stage2(
        const float* __restrict__ h, const float* __restrict__ Wih,
        const float* __restrict__ bih, const float* __restrict__ bhh,
        float* __restrict__ ws) {
    int row = blockIdx.x;
    int t = threadIdx.x;
    const f4* x4 = (const f4*)(ws + WS_Q);   // 296 f4 = [Q | FC6]
    const f4* w0 = (const f4*)Wih + (size_t)row * 296;
    const f4* w1 = (const f4*)Wih + (size_t)(1024 + row) * 296;
    const f4* w2 = (const f4*)Wih + (size_t)(2048 + row) * 296;
    f4 xv = x4[t];
    float a0 = dot4(ntl(w0 + t), xv);
    float a1 = dot4(ntl(w1 + t), xv);
    float a2 = dot4(ntl(w2 + t), xv);
    if (t < 40) {
        int k = 256 + t;
        f4 xw = x4[k];
        a0 += dot4(ntl(w0 + k), xw);
        a1 += dot4(ntl(w1 + k), xw);
        a2 += dot4(ntl(w2 + k), xw);
    }
    a0 = wave_reduce(a0); a1 = wave_reduce(a1); a2 = wave_reduce(a2);
    __shared__ float red[4][3];
    int w = t >> 6, lane = t & 63;
    if (lane == 0) { red[w][0] = a0; red[w][1] = a1; red[w][2] = a2; }
    __syncthreads();
    if (t == 0) {
        float AI0 = red[0][0] + red[1][0] + red[2][0] + red[3][0];
        float AI1 = red[0][1] + red[1][1] + red[2][1] + red[3][1];
        float AI2 = red[0][2] + red[1][2] + red[2][2] + red[3][2];
        float AH0 = ws[WS_AHS + row];
        float AH1 = ws[WS_AHS + row + 1024];
        float AH2 = ws[WS_AHS + row + 2048];
        float gr = AI0 + bih[row]        + AH0 + bhh[row];
        float gz = AI1 + bih[row + 1024] + AH1 + bhh[row + 1024];
        float r = 1.f / (1.f + expf(-gr));
        float z = 1.f / (1.f + expf(-gz));
        float n = tanhf(AI2 + bih[row + 2048] + r * (AH2 + bhh[row + 2048]));
        ws[WS_SIG + row] = (1.f - z) * n + z * h[row];
    }
}

// ---- streaming W1a wave-per-row helper: partial = W1[wid, 0:1024] @ sigma ----
DEV void w1a_wave(int wid, int t, const float* __restrict__ W1, float* __restrict__ ws) {
    int lane = t & 63;
    const f4* w4 = (const f4*)W1 + (size_t)wid * 512;   // first 256 f4 = sigma cols
    const f4* x4 = (const f4*)(ws + WS_SIG);
    float a0 = 0.f, a1 = 0.f;
#pragma unroll
    for (int i = 0; i < 4; ++i) {
        int k = lane + (i << 6);
        float v = dot4(ntl(w4 + k), x4[k]);
        if (i & 1) a1 += v; else a0 += v;
    }
    float a = wave_reduce(a0 + a1);
    if (lane == 0) ws[WS_HID + wid] = a;
}

// ---- K3: FC1 + GRU_S FC7-col partials (blocks 0..1023) | W1a rows 0..40959 ----
__global__ __launch_bounds__(256) void k_stage3(
        const float* __restrict__ W1, const float* __restrict__ fc1w,
        const float* __restrict__ fc1b, const float* __restrict__ WihS,
        float* __restrict__ ws) {
    int t = threadIdx.x;
    if (blockIdx.x < 1024) {
        int row = blockIdx.x;
        const f4* w4 = (const f4*)fc1w + (size_t)row * 256;
        const f4* x4 = (const f4*)(ws + WS_SIG);
        float afc = dot4(ntl(w4 + t), x4[t]);
        const f4* xs4 = (const f4*)(ws + WS_FC7);       // 80 f4
        float u0 = 0.f, u1 = 0.f, u2 = 0.f;
        if (t < 80) {
            f4 xv = xs4[t];
            const f4* s0 = (const f4*)WihS + (size_t)row * 336 + 256;
            const f4* s1 = (const f4*)WihS + (size_t)(1024 + row) * 336 + 256;
            const f4* s2 = (const f4*)WihS + (size_t)(2048 + row) * 336 + 256;
            u0 = dot4(ntl(s0 + t), xv);
            u1 = dot4(ntl(s1 + t), xv);
            u2 = dot4(ntl(s2 + t), xv);
        }
        afc = wave_reduce(afc);
        u0 = wave_reduce(u0); u1 = wave_reduce(u1); u2 = wave_reduce(u2);
        __shared__ float red[4][4];
        int w = t >> 6, lane = t & 63;
        if (lane == 0) { red[w][0] = afc; red[w][1] = u0; red[w][2] = u1; red[w][3] = u2; }
        __syncthreads();
        if (t == 0) {
            ws[WS_FC1 + row] = fmaxf(red[0][0] + red[1][0] + red[2][0] + red[3][0]
                                     + fc1b[row], 0.f);
            ws[WS_AIU + row]        = red[0][1] + red[1][1] + red[2][1] + red[3][1];
            ws[WS_AIU + row + 1024] = red[0][2] + red[1][2] + red[2][2] + red[3][2];
            ws[WS_AIU + row + 2048] = red[0][3] + red[1][3] + red[2][3] + red[3][3];
        }
    } else {
        int wid = ((blockIdx.x - 1024) << 2) + (t >> 6);        // 0..40959
        w1a_wave(wid, t, W1, ws);
    }
}

// ---- K4: GRU_S final (Wih FC1-cols; blocks 0..1023) | W1a rows 40960..81919 ----
__global__ __launch_bounds__(256) void k_stage4(
        const float* __restrict__ W1, const float* __restrict__ h,
        const float* __restrict__ WihS,
        const float* __restrict__ bih, const float* __restrict__ bhh,
        float* __restrict__ ws) {
    int t = threadIdx.x;
    if (blockIdx.x < 1024) {
        int row = blockIdx.x;
        const f4* x4 = (const f4*)(ws + WS_FC1);
        const f4* w0 = (const f4*)WihS + (size_t)row * 336;
        const f4* w1 = (const f4*)WihS + (size_t)(1024 + row) * 336;
        const f4* w2 = (const f4*)WihS + (size_t)(2048 + row) * 336;
        f4 xv = x4[t];
        float a0 = dot4(ntl(w0 + t), xv);
        float a1 = dot4(ntl(w1 + t), xv);
        float a2 = dot4(ntl(w2 + t), xv);
        a0 = wave_reduce(a0); a1 = wave_reduce(a1); a2 = wave_reduce(a2);
        __shared__ float red[4][3];
        int w = t >> 6, lane = t & 63;
        if (lane == 0) { red[w][0] = a0; red[w][1] = a1; red[w][2] = a2; }
        __syncthreads();
        if (t == 0) {
            float AI0 = red[0][0] + red[1][0] + red[2][0] + red[3][0] + ws[WS_AIU + row];
            float AI1 = red[0][1] + red[1][1] + red[2][1] + red[3][1] + ws[WS_AIU + row + 1024];
            float AI2 = red[0][2] + red[1][2] + red[2][2] + red[3][2] + ws[WS_AIU + row + 2048];
            float AH0 = ws[WS_AHU + row];
            float AH1 = ws[WS_AHU + row + 1024];
            float AH2 = ws[WS_AHU + row + 2048];
            float gr = AI0 + bih[row]        + AH0 + bhh[row];
            float gz = AI1 + bih[row + 1024] + AH1 + bhh[row + 1024];
            float r = 1.f / (1.f + expf(-gr));
            float z = 1.f / (1.f + expf(-gz));
            float n = tanhf(AI2 + bih[row + 2048] + r * (AH2 + bhh[row + 2048]));
            ws[WS_S + row] = (1.f - z) * n + z * h[row];
        }
    } else {
        int wid = 40960 + ((blockIdx.x - 1024) << 2) + (t >> 6);
        w1a_wave(wid, t, W1, ws);
    }
}

// ---- K5: hid = relu(partial + W1[:,1024:2048] @ out_S + b1) ----
__global__ __launch_bounds__(256) void k_w1b(
        const float* __restrict__ W1, const float* __restrict__ b1,
        float* __restrict__ ws) {
    int wid = (blockIdx.x << 2) + (threadIdx.x >> 6);
    int lane = threadIdx.x & 63;
    const f4* w4 = (const f4*)W1 + (size_t)wid * 512 + 256;     // cols 1024..2047
    const f4* x4 = (const f4*)(ws + WS_S);
    float a0 = 0.f, a1 = 0.f;
#pragma unroll
    for (int i = 0; i < 4; ++i) {
        int k = lane + (i << 6);
        float v = dot4(ntl(w4 + k), x4[k]);
        if (i & 1) a1 += v; else a0 += v;
    }
    float a = wave_reduce(a0 + a1);
    if (lane == 0) ws[WS_HID + wid] = fmaxf(ws[WS_HID + wid] + a + b1[wid], 0.f);
}

// ---- K6: KG[row] = W2[row] @ hid + b2[row]; out[row>>5] += KG[row] * dy[row&31] ----
__global__ __launch_bounds__(512) void k_w2(
        const float* __restrict__ W2, const float* __restrict__ b2,
        const float* __restrict__ ws, float* __restrict__ out) {
    int row = blockIdx.x;
    int t = threadIdx.x;
    const f4* w4 = (const f4*)W2 + (size_t)row * 20480;
    const f4* x4 = (const f4*)(ws + WS_HID);
    float a0 = 0.f, a1 = 0.f;
#pragma unroll 4
    for (int k = t; k < 20480; k += 512) {
        float v = dot4(ntl(w4 + k), x4[k]);
        if (k & 512) a1 += v; else a0 += v;
    }
    float a = wave_reduce(a0 + a1);
    __shared__ float s[8];
    if ((t & 63) == 0) s[t >> 6] = a;
    __syncthreads();
    if (t == 0) {
        float r = b2[row];
#pragma unroll
        for (int i = 0; i < 8; ++i) r += s[i];
        atomicAdd(&out[row >> 5], r * ws[WS_DY + (row & 31)]);
    }
}

extern "C" void kernel_launch(void* const* d_in, const int* in_sizes, int n_in,
                              void* d_out, int out_size, void* d_ws, size_t ws_size,
                              hipStream_t stream) {
    const float* y          = (const float*)d_in[0];
    const float* post       = (const float*)d_in[1];
    const float* post_prev  = (const float*)d_in[2];
    const float* prior_prev = (const float*)d_in[3];
    const float* y_prev     = (const float*)d_in[4];
    const float* h_Q        = (const float*)d_in[5];
    const float* h_Sigma    = (const float*)d_in[6];
    const float* h_S        = (const float*)d_in[7];
    const float* F          = (const float*)d_in[8];
    const float* Hm         = (const float*)d_in[9];
    const float* FC5_w      = (const float*)d_in[10];
    const float* FC5_b      = (const float*)d_in[11];
    const float* FC6_w      = (const float*)d_in[12];
    const float* FC6_b      = (const float*)d_in[13];
    const float* FC7_w      = (const float*)d_in[14];
    const float* FC7_b      = (const float*)d_in[15];
    const float* GQ_Wih     = (const float*)d_in[16];
    const float* GQ_Whh     = (const float*)d_in[17];
    const float* GQ_bih     = (const float*)d_in[18];
    const float* GQ_bhh     = (const float*)d_in[19];
    const float* GS_Wih     = (const float*)d_in[20];
    const float* GS_Whh     = (const float*)d_in[21];
    const float* GS_bih     = (const float*)d_in[22];
    const float* GS_bhh     = (const float*)d_in[23];
    const float* GU_Wih     = (const float*)d_in[24];
    const float* GU_Whh     = (const float*)d_in[25];
    const float* GU_bih     = (const float*)d_in[26];
    const float* GU_bhh     = (const float*)d_in[27];
    const float* FC1_w      = (const float*)d_in[28];
    const float* FC1_b      = (const float*)d_in[29];
    const float* FC2_w1     = (const float*)d_in[30];
    const float* FC2_b1     = (const float*)d_in[31];
    const float* FC2_w2     = (const float*)d_in[32];
    const float* FC2_b2     = (const float*)d_in[33];
    // d_in[34..37] = FC3/FC4 (dead); d_in[38] = fix_H_flag (always 1)

    float* ws = (float*)d_ws;
    float* out = (float*)d_out;

    // K1: GRU_Q | FC6 | FC7(+priors,dy,out=prior) | Sigma-hh | S-hh
    k_stage1<<<3074, 256, 0, stream>>>(y, y_prev, post, post_prev, prior_prev, F, Hm,
                                       FC5_w, FC5_b, FC6_w, FC6_b, FC7_w, FC7_b,
                                       h_Q, h_Sigma, h_S,
                                       GQ_Wih, GQ_Whh, GQ_bih, GQ_bhh,
                                       GS_Whh, GU_Whh, ws, out);
    // K2: GRU_Sigma (Wih only)
    k_stage2<<<1024, 256, 0, stream>>>(h_Sigma, GS_Wih, GS_bih, GS_bhh, ws);
    // K3: FC1 + GRU_S FC7-partials || W1a rows 0..40959
    k_stage3<<<11264, 256, 0, stream>>>(FC2_w1, FC1_w, FC1_b, GU_Wih, ws);
    // K4: GRU_S final || W1a rows 40960..81919
    k_stage4<<<11264, 256, 0, stream>>>(FC2_w1, h_S, GU_Wih, GU_bih, GU_bhh, ws);
    // K5: hid = relu(partial + W1b @ out_S + b1)
    k_w1b<<<20480, 256, 0, stream>>>(FC2_w1, FC2_b1, ws);
    // K6: KG rows + fused epilogue (atomicAdd into out)
    k_w2<<<1024, 512, 0, stream>>>(FC2_w2, FC2_b2, ws, out);
}